// Round 9
// baseline (151.249 us; speedup 1.0000x reference)
//
#include <hip/hip_runtime.h>
#include <hip/hip_bf16.h>
#include <stdint.h>

// Problem constants: T=512, B=32, I=512, H=512
#define T_DIM 512
#define B_DIM 32
#define K_DIM 512     // I
#define H_DIM 512
#define N_DIM 1536    // 3*H, gate-packed in h-pairs: n = (h>>1)*6 + (h&1)*3 + g
#define M_DIM 16384   // T*B

typedef __bf16 bf16_t;
typedef bf16_t bf16x8 __attribute__((ext_vector_type(8)));
typedef float floatx4 __attribute__((ext_vector_type(4)));

#define LOG2E 1.442695041f     // 1/ln(2)
#define TWO_LOG2E 2.885390082f

// ---------- fp32 -> bf16 (RNE), 8 elems/thread, both inputs fused ----------
// W_ih rows permuted to h-pair gate packing: Wb row (h>>1)*6 + (h&1)*3 + g
// <- original row g*512+h, so each h's 3 gates start 4B-aligned in a C row
// and the scan loads one dwordx2 per step. (R4/R6 lesson: epilogue stores
// must cover full 64B lines or HBM write-amplification eats the savings.)
__device__ __forceinline__ unsigned int f2bf_bits(float f) {
  uint32_t u = __builtin_bit_cast(uint32_t, f);
  u += 0x7FFFu + ((u >> 16) & 1u);
  return u >> 16;
}

__global__ void convert_both_kernel(const float* __restrict__ x,
                                    unsigned short* __restrict__ xb,
                                    const float* __restrict__ W,
                                    unsigned short* __restrict__ Wb) {
  int bid = blockIdx.x;
  const float* src;
  unsigned short* dst;
  int i;
  if (bid < 4096) {           // x: 8388608 elems, identity convert
    i = (bid * 256 + threadIdx.x) * 8;
    src = x + i;
    dst = xb + i;
  } else {                    // Wb: 1536 rows x 512, h-pair permuted
    i = ((bid - 4096) * 256 + threadIdx.x) * 8;
    int n = i >> 9;           // packed row
    int k = i & 511;
    int p6 = n / 6;
    int sub = n - p6 * 6;
    int hodd = (sub >= 3) ? 1 : 0;
    int g = sub - hodd * 3;
    int h = p6 * 2 + hodd;
    src = W + ((g << 9) + h) * 512 + k;
    dst = Wb + i;
  }
  const float4* p = (const float4*)src;
  float4 f0 = p[0];
  float4 f1 = p[1];
  uint4 v;
  v.x = f2bf_bits(f0.x) | (f2bf_bits(f0.y) << 16);
  v.y = f2bf_bits(f0.z) | (f2bf_bits(f0.w) << 16);
  v.z = f2bf_bits(f1.x) | (f2bf_bits(f1.y) << 16);
  v.w = f2bf_bits(f1.z) | (f2bf_bits(f1.w) << 16);
  *(uint4*)dst = v;
}

// ---------- bf16 GEMM: NT, 256x128 tile, BK=64, XOR-swizzled LDS ----------
// A: M x K bf16 (x), Bm: N x K bf16 (W_ih, h-pair packed). C: M x N fp16,
// pre-scaled (gates r,z by -log2e for sigmoid-via-exp2; gate n by +2*log2e).
// 512 threads = 8 waves (4 M x 2 N), each wave 64x64 via 4x4 16x16x32 MFMAs.
// ~33 us at 25.8 GF ~= the m97-structure plateau; left unchanged this round.
__global__ __launch_bounds__(512, 4) void gemm_bf16_kernel(
    const unsigned short* __restrict__ A, const unsigned short* __restrict__ Bm,
    _Float16* __restrict__ C) {
  __shared__ bf16_t smem[24576];  // [0..16383] A-tile 256x64, [16384..] B-tile
  const int tid = threadIdx.x;
  const int lane = tid & 63;
  const int w = tid >> 6;
  const int tileM = blockIdx.x * 256;
  const int tileN = blockIdx.y * 128;
  const int waveM = w & 3;
  const int waveN = w >> 2;
  const int lm = lane & 15;
  const int lg = lane >> 4;       // 0..3 k-chunk group

  floatx4 acc[4][4] = {};

  for (int k0 = 0; k0 < K_DIM; k0 += 64) {
    // A: 2048 16B chunks (256 rows x 8), 4 groups of 512
#pragma unroll
    for (int g = 0; g < 4; ++g) {
      int s = g * 512 + tid;
      int row = s >> 3;
      int kc = (s & 7) ^ (row & 7);  // source chunk under swizzle
      bf16_t* la = smem + (g * 512 + w * 64) * 8;
      const unsigned short* ga = A + (size_t)(tileM + row) * K_DIM + k0 + kc * 8;
      __builtin_amdgcn_global_load_lds(
          (const __attribute__((address_space(1))) unsigned int*)ga,
          (__attribute__((address_space(3))) unsigned int*)la, 16, 0, 0);
    }
    // B: 1024 chunks (128 rows x 8), 2 groups of 512
#pragma unroll
    for (int g = 0; g < 2; ++g) {
      int s = g * 512 + tid;
      int row = s >> 3;
      int kc = (s & 7) ^ (row & 7);
      bf16_t* lb = smem + 16384 + (g * 512 + w * 64) * 8;
      const unsigned short* gb = Bm + (size_t)(tileN + row) * K_DIM + k0 + kc * 8;
      __builtin_amdgcn_global_load_lds(
          (const __attribute__((address_space(1))) unsigned int*)gb,
          (__attribute__((address_space(3))) unsigned int*)lb, 16, 0, 0);
    }
    __syncthreads();

#pragma unroll
    for (int ks = 0; ks < 2; ++ks) {
      bf16x8 af[4], bfg[4];
#pragma unroll
      for (int i = 0; i < 4; ++i) {
        int row = waveM * 64 + i * 16 + lm;
        int c = ks * 4 + lg;
        af[i] = *(const bf16x8*)(smem + row * 64 + (c ^ (row & 7)) * 8);
      }
#pragma unroll
      for (int j = 0; j < 4; ++j) {
        int row = waveN * 64 + j * 16 + lm;
        int c = ks * 4 + lg;
        bfg[j] = *(const bf16x8*)(smem + 16384 + row * 64 + (c ^ (row & 7)) * 8);
      }
#pragma unroll
      for (int i = 0; i < 4; ++i)
#pragma unroll
        for (int j = 0; j < 4; ++j)
          acc[i][j] = __builtin_amdgcn_mfma_f32_16x16x32_bf16(af[i], bfg[j],
                                                              acc[i][j], 0, 0, 0);
    }
    __syncthreads();  // also guarantees smem reusable for the epilogue
  }

  // Epilogue. MFMA C/D layout: col=lane&15 (+16j), row=(lane>>4)*4+reg (+16i).
  // Two passes of 32 rows through a 4KB wave-private LDS region, read back as
  // 4-col quads -> 16 lanes x 8B = 128B contiguous stores (full lines).
  _Float16* ep = (_Float16*)smem + w * 2048;  // 32x64 fp16 per wave
  const int q = lm;            // col quad 0..15
  const int rgrp = lane >> 4;  // 0..3
  const size_t crow0 = (size_t)(tileM + waveM * 64);
  const int ccol = tileN + waveN * 64 + q * 4;
#pragma unroll
  for (int p = 0; p < 2; ++p) {
#pragma unroll
    for (int il = 0; il < 2; ++il) {
      const int i = 2 * p + il;
#pragma unroll
      for (int j = 0; j < 4; ++j) {
        const int cl = lm + j * 16;
        const int sub = (tileN + waveN * 64 + cl) % 6;
        const float scl = (sub == 2 || sub == 5) ? TWO_LOG2E : -LOG2E;
#pragma unroll
        for (int r = 0; r < 4; ++r) {
          int rl = (lane >> 4) * 4 + r + 16 * il;  // 0..31
          ep[rl * 64 + cl] = (_Float16)(scl * acc[i][j][r]);
        }
      }
    }
    // wave-private region: DS ops within a wave are ordered; no barrier
#pragma unroll
    for (int k = 0; k < 8; ++k) {
      int rl = rgrp + 4 * k;  // 0..31
      uint2 v = *(const uint2*)(ep + rl * 64 + q * 4);
      *(uint2*)(C + (crow0 + p * 32 + rl) * N_DIM + ccol) = v;
    }
  }
}

// ---------- diagonal GRU scan, block-pipelined ----------
// gx fp16 h-pair packed: gates (gr',gz',gn') of (m,h) start at byte
// (h>>1)*12 + (h&1)*4 in row m. One dwordx2 per step, h-parity funnel shift.
// Pre-scaled (gr',gz' by -log2e; gn' by 2*log2e):
// sigmoid(x)=rcp(1+exp2(-log2e*x)); tanh(y)=1-2*rcp(exp2(2*log2e*y)+1).
// R8 lesson: per-step interleaved load+store = 2 vmcnt entries/step; at D=32
// the wait window (64) exceeds vmcnt's 6-bit max -> conservative waits.
// Restructure: double-buffered 16-step blocks — burst 16 loads, compute 16
// steps pure-ALU from the other buffer, burst 16 stores from a reg stash.
// Waits are vmcnt(<=31); prefetch distance = 1 block (~1200 cy > 900 HBM),
// pinned with memory clobbers (R3 lesson).
__device__ __forceinline__ float gru_step(uint2 q, int sh, float wr, float wz,
                                          float wn, float hv) {
  uint64_t v = (((uint64_t)q.y << 32) | q.x) >> sh;
  float gr = (float)__builtin_bit_cast(_Float16, (unsigned short)v);
  float gz = (float)__builtin_bit_cast(_Float16, (unsigned short)(v >> 16));
  float gn = (float)__builtin_bit_cast(_Float16, (unsigned short)(v >> 32));
  float ar = fmaf(wr, hv, gr);
  float az = fmaf(wz, hv, gz);
  float t1 = wn * hv;
  float er = __builtin_amdgcn_exp2f(ar);
  float ez = __builtin_amdgcn_exp2f(az);
  float r = __builtin_amdgcn_rcpf(1.0f + er);
  float z = __builtin_amdgcn_rcpf(1.0f + ez);
  float en = __builtin_amdgcn_exp2f(fmaf(r, t1, gn));
  float u = __builtin_amdgcn_rcpf(1.0f + en);
  float n = fmaf(-2.0f, u, 1.0f);
  float zh = z * hv;
  float omz = 1.0f - z;
  return fmaf(n, omz, zh);
}

__global__ __launch_bounds__(64) void indgru_scan_kernel(
    const _Float16* __restrict__ gx, const float* __restrict__ h0,
    const float* __restrict__ w_hh, float* __restrict__ out,
    float* __restrict__ hlast) {
  const int idx = blockIdx.x * 64 + threadIdx.x;  // 0..16383
  const int b = idx >> 9;
  const int h = idx & (H_DIM - 1);
  const float wr = -LOG2E * w_hh[h];
  const float wz = -LOG2E * w_hh[H_DIM + h];
  const float wn = TWO_LOG2E * w_hh[2 * H_DIM + h];
  const int sh = (h & 1) << 4;  // funnel shift: 0 or 16 bits
  float hv = h0[idx];

  // byte-exact base: fp16 index m*1536 + (h>>1)*6, then +4B if h odd
  const char* base = (const char*)(gx + (size_t)b * N_DIM + (h >> 1) * 6) + ((h & 1) << 2);
  float* outp = out + (size_t)b * H_DIM + h;  // t-stride 16384 fp32

  constexpr int DB = 16;
  constexpr size_t TSTRIDE = (size_t)B_DIM * N_DIM * sizeof(_Float16);  // 98304 B
  uint2 bufA[DB], bufB[DB];
  float hs[DB];

  // preload block 0
#pragma unroll
  for (int s = 0; s < DB; ++s)
    bufA[s] = *(const uint2*)(base + (size_t)s * TSTRIDE);
  asm volatile("" ::: "memory");

  for (int t0 = 0; t0 < T_DIM; t0 += 2 * DB) {  // 16 iterations
    // ---- even half: prefetch into B, compute from A ----
#pragma unroll
    for (int s = 0; s < DB; ++s)
      bufB[s] = *(const uint2*)(base + (size_t)(t0 + DB + s) * TSTRIDE);
    asm volatile("" ::: "memory");
#pragma unroll
    for (int s = 0; s < DB; ++s) {
      hv = gru_step(bufA[s], sh, wr, wz, wn, hv);
      hs[s] = hv;
    }
#pragma unroll
    for (int s = 0; s < DB; ++s)
      outp[(size_t)(t0 + s) * (B_DIM * H_DIM)] = hs[s];
    asm volatile("" ::: "memory");
    // ---- odd half: prefetch into A (guarded), compute from B ----
    if (t0 + 2 * DB < T_DIM) {
#pragma unroll
      for (int s = 0; s < DB; ++s)
        bufA[s] = *(const uint2*)(base + (size_t)(t0 + 2 * DB + s) * TSTRIDE);
    }
    asm volatile("" ::: "memory");
#pragma unroll
    for (int s = 0; s < DB; ++s) {
      hv = gru_step(bufB[s], sh, wr, wz, wn, hv);
      hs[s] = hv;
    }
#pragma unroll
    for (int s = 0; s < DB; ++s)
      outp[(size_t)(t0 + DB + s) * (B_DIM * H_DIM)] = hs[s];
    asm volatile("" ::: "memory");
  }
  hlast[idx] = hv;
}

extern "C" void kernel_launch(void* const* d_in, const int* in_sizes, int n_in,
                              void* d_out, int out_size, void* d_ws, size_t ws_size,
                              hipStream_t stream) {
  const float* x    = (const float*)d_in[0];   // (T,B,I)  = 8388608
  const float* h0   = (const float*)d_in[1];   // (B,H)    = 16384
  const float* W_ih = (const float*)d_in[2];   // (3H,I)   = 786432
  const float* w_hh = (const float*)d_in[3];   // (3,H)    = 1536

  float* out = (float*)d_out;                          // (T,B,H)
  float* hlast = out + (size_t)T_DIM * B_DIM * H_DIM;  // (1,B,H)

  // workspace: xb(bf16) 16 MB | Wb(bf16 1536x512) 1.5 MB | gx(fp16) 50 MB
  char* ws = (char*)d_ws;
  unsigned short* xb = (unsigned short*)ws;
  unsigned short* Wb = (unsigned short*)(ws + 16777216);
  _Float16* gx = (_Float16*)(ws + 16777216 + 1572864);

  convert_both_kernel<<<4480, 256, 0, stream>>>(x, xb, W_ih, Wb);

  dim3 grid(M_DIM / 256, N_DIM / 128);  // 64 x 12
  gemm_bf16_kernel<<<grid, 512, 0, stream>>>(xb, Wb, gx);

  indgru_scan_kernel<<<256, 64, 0, stream>>>(gx, h0, w_hh, out, hlast);
}